// Round 8
// baseline (299.024 us; speedup 1.0000x reference)
//
#include <hip/hip_runtime.h>
#include <hip/hip_bf16.h>

#define Bdim 16
#define Cdim 512
#define Mdim 256
#define Ndim 4096

typedef short bf16x8 __attribute__((ext_vector_type(8)));
typedef float f32x4 __attribute__((ext_vector_type(4)));
typedef unsigned short us8 __attribute__((ext_vector_type(8)));
typedef unsigned short us4 __attribute__((ext_vector_type(4)));

// round-half-up f32 -> bf16 (tie bias only vs RNE)
__device__ __forceinline__ unsigned short f2b(float f) {
  union { float f; unsigned int u; } v; v.f = f;
  return (unsigned short)((v.u + 0x8000u) >> 16);
}
__device__ __forceinline__ float b2f(unsigned short h) {
  union { unsigned int u; float f; } v; v.u = ((unsigned int)h) << 16;
  return v.f;
}

// ---------------- K0: one-time Wk f32 -> bf16 ------------------------------
__global__ __launch_bounds__(256) void k0_convert(
    const float* __restrict__ gWk, unsigned short* __restrict__ oWk) {
  const int i = (blockIdx.x * 256 + threadIdx.x) * 4;
  f32x4 a = *reinterpret_cast<const f32x4*>(gWk + i);
  us4 ha;
#pragma unroll
  for (int j = 0; j < 4; ++j) ha[j] = f2b(a[j]);
  *reinterpret_cast<us4*>(oWk + i) = ha;
}

// ---------------- K0b: prepack Wv into MFMA A-fragment order ---------------
// WvF[fb][lane][8], fb = (c>>4)*8 + (m>>5):
//   WvF[fb][lane][j] = Wv[c16*16 + (lane&15)][mb*32 + (lane>>4)*8 + j]
// A wave's fragment load becomes one contiguous 1KB dwordx4.
__global__ __launch_bounds__(256) void k0b_prepack(
    const float* __restrict__ gWv, unsigned short* __restrict__ oWvF) {
  const int gid = blockIdx.x * 256 + threadIdx.x;   // 16384 threads
  const int lane = gid & 63;
  const int fb = gid >> 6;
  const int c16 = fb >> 3;
  const int mb = fb & 7;
  const int c = c16 * 16 + (lane & 15);
  const int m = mb * 32 + (lane >> 4) * 8;
  const float* src = gWv + (size_t)c * Mdim + m;
  f32x4 v0 = *reinterpret_cast<const f32x4*>(src);
  f32x4 v1 = *reinterpret_cast<const f32x4*>(src + 4);
  us8 h;
#pragma unroll
  for (int j = 0; j < 4; ++j) { h[j] = f2b(v0[j]); h[4 + j] = f2b(v1[j]); }
  *reinterpret_cast<us8*>(oWvF + (size_t)gid * 8) = h;
}

// ---------------- K1: S[b,m,n] = sum_c Wk[m,c] * x[b,c,n]  (bf16 MFMA) ----
#define K1_XPAD 72

__global__ __launch_bounds__(256) void k1_gemm1(
    const float* __restrict__ gx, const unsigned short* __restrict__ gWkB,
    unsigned short* __restrict__ gS) {
  __shared__ unsigned short Wk_s[128 * 64];        // [m][c] linear, swizzled
  __shared__ unsigned short xT_s[128 * K1_XPAD];   // [n][c] padded
  const int t = threadIdx.x;
  const int b = blockIdx.z;
  const int m0 = blockIdx.y * 128;
  const int n0 = blockIdx.x * 128;
  const int w = t >> 6;
  const int lane = t & 63;
  const int lr = lane & 15;
  const int lg = lane >> 4;
  const int wm = (w >> 1) * 64;
  const int wn = (w & 1) * 64;

  f32x4 acc[4][4] = {};
  const float* xb = gx + (size_t)b * Cdim * Ndim + n0;

  const int snl = t & 63;          // staging: n within half-tile
  const int scb = (t >> 6) * 16;   // staging: c block (wave-uniform)
  const int wrow = lane >> 3;
  const int wchk = (lane & 7) ^ (wrow & 7);

  for (int ck = 0; ck < Cdim; ck += 64) {
    {
      const unsigned short* gsrc =
          gWkB + (size_t)(m0 + w * 32 + wrow) * Cdim + ck + wchk * 8;
#pragma unroll
      for (int j = 0; j < 4; ++j) {
        __builtin_amdgcn_global_load_lds(
            (const __attribute__((address_space(1))) unsigned int*)(gsrc + (size_t)j * 8 * Cdim),
            (__attribute__((address_space(3))) unsigned int*)&Wk_s[(w * 32 + j * 8) * 64],
            16, 0, 0);
      }
    }
#pragma unroll
    for (int h = 0; h < 2; ++h) {
      const int n = snl + h * 64;
      const float* src = xb + (size_t)(ck + scb) * Ndim + n;
      float xv[16];
#pragma unroll
      for (int j = 0; j < 16; ++j) xv[j] = src[(size_t)j * Ndim];
      us8 h0, h1;
#pragma unroll
      for (int j = 0; j < 8; ++j) {
        h0[j] = (unsigned short)(__float_as_uint(xv[j]) >> 16);
        h1[j] = (unsigned short)(__float_as_uint(xv[8 + j]) >> 16);
      }
      *reinterpret_cast<us8*>(&xT_s[n * K1_XPAD + scb]) = h0;
      *reinterpret_cast<us8*>(&xT_s[n * K1_XPAD + scb + 8]) = h1;
    }
    __syncthreads();
#pragma unroll
    for (int kk = 0; kk < 64; kk += 32) {
      bf16x8 af[4], bfr[4];
#pragma unroll
      for (int mi = 0; mi < 4; ++mi) {
        const int rm = wm + mi * 16 + lr;
        af[mi] = *reinterpret_cast<const bf16x8*>(
            reinterpret_cast<const char*>(Wk_s) +
            rm * 128 + ((kk * 2 + lg * 16) ^ ((rm & 7) << 4)));
      }
#pragma unroll
      for (int ni = 0; ni < 4; ++ni)
        bfr[ni] = *reinterpret_cast<const bf16x8*>(
            &xT_s[(wn + ni * 16 + lr) * K1_XPAD + kk + lg * 8]);
#pragma unroll
      for (int mi = 0; mi < 4; ++mi)
#pragma unroll
        for (int ni = 0; ni < 4; ++ni)
          acc[mi][ni] = __builtin_amdgcn_mfma_f32_16x16x32_bf16(
              af[mi], bfr[ni], acc[mi][ni], 0, 0, 0);
    }
    __syncthreads();
  }
  unsigned short* Sb = gS + ((size_t)b * Mdim + m0 + wm) * Ndim + n0 + wn;
#pragma unroll
  for (int mi = 0; mi < 4; ++mi)
#pragma unroll
    for (int ni = 0; ni < 4; ++ni)
#pragma unroll
      for (int r = 0; r < 4; ++r) {
        int m = mi * 16 + lg * 4 + r;
        int n = ni * 16 + lr;
        Sb[(size_t)m * Ndim + n] = f2b(acc[mi][ni][r]);
      }
}

// ---------------- K2: per-(b,m) row max and 1/sum(exp) ---------------------
__global__ __launch_bounds__(256) void k2_rowstats(
    const unsigned short* __restrict__ gS, float2* __restrict__ stats) {
  const int m = blockIdx.x;
  const int b = blockIdx.y;
  const unsigned short* row = gS + ((size_t)b * Mdim + m) * Ndim;
  const int t = threadIdx.x;
  const int w = t >> 6;
  float v[16];
#pragma unroll
  for (int i = 0; i < 2; ++i) {
    us8 u = *reinterpret_cast<const us8*>(row + i * 2048 + t * 8);
#pragma unroll
    for (int j = 0; j < 8; ++j) v[i * 8 + j] = b2f(u[j]);
  }
  float mx = -1e30f;
#pragma unroll
  for (int i = 0; i < 16; ++i) mx = fmaxf(mx, v[i]);
#pragma unroll
  for (int o = 32; o > 0; o >>= 1) mx = fmaxf(mx, __shfl_xor(mx, o, 64));
  __shared__ float redmax[4], redsum[4];
  if ((t & 63) == 0) redmax[w] = mx;
  __syncthreads();
  mx = fmaxf(fmaxf(redmax[0], redmax[1]), fmaxf(redmax[2], redmax[3]));
  float s = 0.f;
#pragma unroll
  for (int i = 0; i < 16; ++i) s += __expf(v[i] - mx);
#pragma unroll
  for (int o = 32; o > 0; o >>= 1) s += __shfl_xor(s, o, 64);
  if ((t & 63) == 0) redsum[w] = s;
  __syncthreads();
  if (t == 0) {
    float tot = redsum[0] + redsum[1] + redsum[2] + redsum[3];
    stats[(size_t)b * Mdim + m] = make_float2(mx, 1.0f / tot);
  }
}

// ---------------- K3: softmax + L1-normalize over M, write PT[b][n][m] -----
#define K3_PAD 264

__global__ __launch_bounds__(256) void k3_norm(
    const unsigned short* __restrict__ gS, const float2* __restrict__ stats,
    unsigned short* __restrict__ gPT) {
  __shared__ unsigned short P_s[64 * K3_PAD];
  __shared__ float cs[4][64];
  __shared__ float rtot[64];
  const int b = blockIdx.y;
  const int n0 = blockIdx.x * 64;
  const int t = threadIdx.x;
  const int w = t >> 6;
  const int l = t & 63;
  const unsigned short* Sb = gS + ((size_t)b * Mdim + w * 64) * Ndim + n0 + l;
  const float2* stb = stats + (size_t)b * Mdim + w * 64;
  float acc = 0.f;
#pragma unroll
  for (int i8 = 0; i8 < 8; ++i8) {
    us8 pk;
#pragma unroll
    for (int jj = 0; jj < 8; ++jj) {
      const int mi = i8 * 8 + jj;
      float2 st = stb[mi];
      float p = __expf(b2f(Sb[(size_t)mi * Ndim]) - st.x) * st.y;
      acc += p;
      pk[jj] = f2b(p);
    }
    *reinterpret_cast<us8*>(&P_s[l * K3_PAD + w * 64 + i8 * 8]) = pk;
  }
  cs[w][l] = acc;
  __syncthreads();
  if (w == 0) rtot[l] = 1.0f / (1e-9f + cs[0][l] + cs[1][l] + cs[2][l] + cs[3][l]);
  __syncthreads();
  const int mo = (t & 31) * 8;
#pragma unroll
  for (int j = 0; j < 8; ++j) {
    const int n = (t >> 5) + j * 8;
    const float rc = rtot[n];
    us8 pv = *reinterpret_cast<const us8*>(&P_s[n * K3_PAD + mo]);
    us8 o;
#pragma unroll
    for (int q = 0; q < 8; ++q) o[q] = f2b(b2f(pv[q]) * rc);
    *reinterpret_cast<us8*>(gPT + ((size_t)b * Ndim + n0 + n) * Mdim + mo) = o;
  }
}

// ---------------- K4: out = x + Wv * Pn  (TLP + prepacked Wv) --------------
// Grid (N/64, B) = 1024 blocks. 32KB LDS -> 4 blocks/CU, 16 waves/CU.
// PT[n0..+63][0..255] staged once (global_load_lds, source pre-swizzle
// chunk ^= row&7). Block covers all 512 c via 2 slabs x (4 waves x 64c).
// Wv A-frags from prepacked WvF: one contiguous 1KB dwordx4 per fragment.
__global__ __launch_bounds__(256, 4) void k4_gemm2(
    const float* __restrict__ gx, const unsigned short* __restrict__ gWvF,
    const unsigned short* __restrict__ gPT, float* __restrict__ gout) {
  __shared__ unsigned short PT_s[64 * 256];  // [n][m] swizzled, 32KB
  const int t = threadIdx.x;
  const int b = blockIdx.y;
  const int n0 = blockIdx.x * 64;
  const int w = t >> 6;
  const int lane = t & 63;
  const int lr = lane & 15;
  const int lg = lane >> 4;

  // ---- stage PT once: per wave 8 instrs, each 1KB = 2 rows of 512B.
  {
    const int rsub = lane >> 5;   // 0..1
    const int q = lane & 31;      // 16B chunk within row
#pragma unroll
    for (int j = 0; j < 8; ++j) {
      const int row = w * 16 + j * 2 + rsub;
      __builtin_amdgcn_global_load_lds(
          (const __attribute__((address_space(1))) unsigned int*)(
              gPT + ((size_t)b * Ndim + n0 + row) * Mdim + (q ^ (row & 7)) * 8),
          (__attribute__((address_space(3))) unsigned int*)&PT_s[(w * 16 + j * 2) * 256],
          16, 0, 0);
    }
  }
  __syncthreads();

  const char* pts = reinterpret_cast<const char*>(PT_s);

#pragma unroll 1
  for (int c0 = 0; c0 < 2; ++c0) {
    f32x4 acc[4][4] = {};
    // fragment base for this wave's 64 c-rows: c16base = c0*16 + w*4
    const unsigned short* wvf =
        gWvF + ((size_t)(c0 * 16 + w * 4) * 8 * 64 + lane) * 8;
#pragma unroll
    for (int kt = 0; kt < 4; ++kt) {
      bf16x8 a[4][2];
#pragma unroll
      for (int ci = 0; ci < 4; ++ci)
#pragma unroll
        for (int q = 0; q < 2; ++q)
          a[ci][q] = *reinterpret_cast<const bf16x8*>(
              wvf + (size_t)(ci * 8 + kt * 2 + q) * 512);
#pragma unroll
      for (int q = 0; q < 2; ++q) {
        const int kkb = kt * 128 + q * 64 + lg * 16;  // byte col in 512B row
        bf16x8 bfr[4];
#pragma unroll
        for (int ni = 0; ni < 4; ++ni) {
          const int rn = ni * 16 + lr;
          bfr[ni] = *reinterpret_cast<const bf16x8*>(
              pts + rn * 512 + (kkb ^ ((rn & 7) << 4)));
        }
#pragma unroll
        for (int ci = 0; ci < 4; ++ci)
#pragma unroll
          for (int ni = 0; ni < 4; ++ni)
            acc[ci][ni] = __builtin_amdgcn_mfma_f32_16x16x32_bf16(
                a[ci][q], bfr[ni], acc[ci][ni], 0, 0, 0);
      }
    }
    // epilogue for this c0 slab (256 c-rows, this wave's 64)
    const size_t base = ((size_t)b * Cdim + c0 * 256 + w * 64) * Ndim + n0;
#pragma unroll
    for (int ci = 0; ci < 4; ++ci)
#pragma unroll
      for (int ni = 0; ni < 4; ++ni)
#pragma unroll
        for (int r = 0; r < 4; ++r) {
          size_t idx = base + (size_t)(ci * 16 + lg * 4 + r) * Ndim + ni * 16 + lr;
          gout[idx] = gx[idx] + acc[ci][ni][r];
        }
  }
}

extern "C" void kernel_launch(void* const* d_in, const int* in_sizes, int n_in,
                              void* d_out, int out_size, void* d_ws, size_t ws_size,
                              hipStream_t stream) {
  const float* x = (const float*)d_in[0];
  const float* Wk = (const float*)d_in[1];
  const float* Wv = (const float*)d_in[2];
  float* out = (float*)d_out;

  unsigned short* S = (unsigned short*)d_ws;                    // [B][M][N] bf16
  unsigned short* PT = S + (size_t)Bdim * Mdim * Ndim;          // [B][N][M] bf16
  float2* stats = (float2*)(PT + (size_t)Bdim * Ndim * Mdim);   // [B][M]
  unsigned short* WkB = (unsigned short*)(stats + Bdim * Mdim); // [M][C] bf16
  unsigned short* WvF = WkB + Mdim * Cdim;                      // prepacked frags

  k0_convert<<<dim3((Mdim * Cdim) / 1024), 256, 0, stream>>>(Wk, WkB);
  k0b_prepack<<<dim3(64), 256, 0, stream>>>(Wv, WvF);
  k1_gemm1<<<dim3(Ndim / 128, Mdim / 128, Bdim), 256, 0, stream>>>(x, WkB, S);
  k2_rowstats<<<dim3(Mdim, Bdim), 256, 0, stream>>>(S, stats);
  k3_norm<<<dim3(Ndim / 64, Bdim), 256, 0, stream>>>(S, stats, PT);
  k4_gemm2<<<dim3(Ndim / 64, Bdim), 256, 0, stream>>>(x, WvF, PT, out);
}

// Round 9
// 122.717 us; speedup vs baseline: 2.4367x; 2.4367x over previous
//
#include <hip/hip_runtime.h>
#include <hip/hip_bf16.h>

#define Bdim 16
#define Cdim 512
#define Mdim 256
#define Ndim 4096

typedef short bf16x8 __attribute__((ext_vector_type(8)));
typedef float f32x4 __attribute__((ext_vector_type(4)));
typedef unsigned short us8 __attribute__((ext_vector_type(8)));
typedef unsigned short us4 __attribute__((ext_vector_type(4)));

// round-half-up f32 -> bf16 (tie bias only vs RNE)
__device__ __forceinline__ unsigned short f2b(float f) {
  union { float f; unsigned int u; } v; v.f = f;
  return (unsigned short)((v.u + 0x8000u) >> 16);
}
__device__ __forceinline__ float b2f(unsigned short h) {
  union { unsigned int u; float f; } v; v.u = ((unsigned int)h) << 16;
  return v.f;
}

// ---------------- K0: one-time Wk,Wv f32 -> bf16 (512 KB total) -----------
__global__ __launch_bounds__(256) void k0_convert(
    const float* __restrict__ gWk, const float* __restrict__ gWv,
    unsigned short* __restrict__ oWk, unsigned short* __restrict__ oWv) {
  const int i = (blockIdx.x * 256 + threadIdx.x) * 4;
  f32x4 a = *reinterpret_cast<const f32x4*>(gWk + i);
  f32x4 b = *reinterpret_cast<const f32x4*>(gWv + i);
  us4 ha, hb;
#pragma unroll
  for (int j = 0; j < 4; ++j) { ha[j] = f2b(a[j]); hb[j] = f2b(b[j]); }
  *reinterpret_cast<us4*>(oWk + i) = ha;
  *reinterpret_cast<us4*>(oWv + i) = hb;
}

// ---------------- K1: S[b,m,n] = sum_c Wk[m,c] * x[b,c,n]  (bf16 MFMA) ----
#define K1_XPAD 72

__global__ __launch_bounds__(256) void k1_gemm1(
    const float* __restrict__ gx, const unsigned short* __restrict__ gWkB,
    unsigned short* __restrict__ gS) {
  __shared__ unsigned short Wk_s[128 * 64];        // [m][c] linear, swizzled
  __shared__ unsigned short xT_s[128 * K1_XPAD];   // [n][c] padded
  const int t = threadIdx.x;
  const int b = blockIdx.z;
  const int m0 = blockIdx.y * 128;
  const int n0 = blockIdx.x * 128;
  const int w = t >> 6;
  const int lane = t & 63;
  const int lr = lane & 15;
  const int lg = lane >> 4;
  const int wm = (w >> 1) * 64;
  const int wn = (w & 1) * 64;

  f32x4 acc[4][4] = {};
  const float* xb = gx + (size_t)b * Cdim * Ndim + n0;

  const int snl = t & 63;          // staging: n within half-tile
  const int scb = (t >> 6) * 16;   // staging: c block (wave-uniform)
  const int wrow = lane >> 3;
  const int wchk = (lane & 7) ^ (wrow & 7);

  for (int ck = 0; ck < Cdim; ck += 64) {
    {
      const unsigned short* gsrc =
          gWkB + (size_t)(m0 + w * 32 + wrow) * Cdim + ck + wchk * 8;
#pragma unroll
      for (int j = 0; j < 4; ++j) {
        __builtin_amdgcn_global_load_lds(
            (const __attribute__((address_space(1))) unsigned int*)(gsrc + (size_t)j * 8 * Cdim),
            (__attribute__((address_space(3))) unsigned int*)&Wk_s[(w * 32 + j * 8) * 64],
            16, 0, 0);
      }
    }
#pragma unroll
    for (int h = 0; h < 2; ++h) {
      const int n = snl + h * 64;
      const float* src = xb + (size_t)(ck + scb) * Ndim + n;
      float xv[16];
#pragma unroll
      for (int j = 0; j < 16; ++j) xv[j] = src[(size_t)j * Ndim];
      us8 h0, h1;
#pragma unroll
      for (int j = 0; j < 8; ++j) {
        h0[j] = (unsigned short)(__float_as_uint(xv[j]) >> 16);
        h1[j] = (unsigned short)(__float_as_uint(xv[8 + j]) >> 16);
      }
      *reinterpret_cast<us8*>(&xT_s[n * K1_XPAD + scb]) = h0;
      *reinterpret_cast<us8*>(&xT_s[n * K1_XPAD + scb + 8]) = h1;
    }
    __syncthreads();
#pragma unroll
    for (int kk = 0; kk < 64; kk += 32) {
      bf16x8 af[4], bfr[4];
#pragma unroll
      for (int mi = 0; mi < 4; ++mi) {
        const int rm = wm + mi * 16 + lr;
        af[mi] = *reinterpret_cast<const bf16x8*>(
            reinterpret_cast<const char*>(Wk_s) +
            rm * 128 + ((kk * 2 + lg * 16) ^ ((rm & 7) << 4)));
      }
#pragma unroll
      for (int ni = 0; ni < 4; ++ni)
        bfr[ni] = *reinterpret_cast<const bf16x8*>(
            &xT_s[(wn + ni * 16 + lr) * K1_XPAD + kk + lg * 8]);
#pragma unroll
      for (int mi = 0; mi < 4; ++mi)
#pragma unroll
        for (int ni = 0; ni < 4; ++ni)
          acc[mi][ni] = __builtin_amdgcn_mfma_f32_16x16x32_bf16(
              af[mi], bfr[ni], acc[mi][ni], 0, 0, 0);
    }
    __syncthreads();
  }
  unsigned short* Sb = gS + ((size_t)b * Mdim + m0 + wm) * Ndim + n0 + wn;
#pragma unroll
  for (int mi = 0; mi < 4; ++mi)
#pragma unroll
    for (int ni = 0; ni < 4; ++ni)
#pragma unroll
      for (int r = 0; r < 4; ++r) {
        int m = mi * 16 + lg * 4 + r;
        int n = ni * 16 + lr;
        Sb[(size_t)m * Ndim + n] = f2b(acc[mi][ni][r]);
      }
}

// ---------------- K2: per-(b,m) row max and 1/sum(exp) ---------------------
__global__ __launch_bounds__(256) void k2_rowstats(
    const unsigned short* __restrict__ gS, float2* __restrict__ stats) {
  const int m = blockIdx.x;
  const int b = blockIdx.y;
  const unsigned short* row = gS + ((size_t)b * Mdim + m) * Ndim;
  const int t = threadIdx.x;
  const int w = t >> 6;
  float v[16];
#pragma unroll
  for (int i = 0; i < 2; ++i) {
    us8 u = *reinterpret_cast<const us8*>(row + i * 2048 + t * 8);
#pragma unroll
    for (int j = 0; j < 8; ++j) v[i * 8 + j] = b2f(u[j]);
  }
  float mx = -1e30f;
#pragma unroll
  for (int i = 0; i < 16; ++i) mx = fmaxf(mx, v[i]);
#pragma unroll
  for (int o = 32; o > 0; o >>= 1) mx = fmaxf(mx, __shfl_xor(mx, o, 64));
  __shared__ float redmax[4], redsum[4];
  if ((t & 63) == 0) redmax[w] = mx;
  __syncthreads();
  mx = fmaxf(fmaxf(redmax[0], redmax[1]), fmaxf(redmax[2], redmax[3]));
  float s = 0.f;
#pragma unroll
  for (int i = 0; i < 16; ++i) s += __expf(v[i] - mx);
#pragma unroll
  for (int o = 32; o > 0; o >>= 1) s += __shfl_xor(s, o, 64);
  if ((t & 63) == 0) redsum[w] = s;
  __syncthreads();
  if (t == 0) {
    float tot = redsum[0] + redsum[1] + redsum[2] + redsum[3];
    stats[(size_t)b * Mdim + m] = make_float2(mx, 1.0f / tot);
  }
}

// ---------------- K3: softmax + L1-normalize over M, write PT[b][n][m] -----
#define K3_PAD 264

__global__ __launch_bounds__(256) void k3_norm(
    const unsigned short* __restrict__ gS, const float2* __restrict__ stats,
    unsigned short* __restrict__ gPT) {
  __shared__ unsigned short P_s[64 * K3_PAD];
  __shared__ float cs[4][64];
  __shared__ float rtot[64];
  const int b = blockIdx.y;
  const int n0 = blockIdx.x * 64;
  const int t = threadIdx.x;
  const int w = t >> 6;
  const int l = t & 63;
  const unsigned short* Sb = gS + ((size_t)b * Mdim + w * 64) * Ndim + n0 + l;
  const float2* stb = stats + (size_t)b * Mdim + w * 64;
  float acc = 0.f;
#pragma unroll
  for (int i8 = 0; i8 < 8; ++i8) {
    us8 pk;
#pragma unroll
    for (int jj = 0; jj < 8; ++jj) {
      const int mi = i8 * 8 + jj;
      float2 st = stb[mi];
      float p = __expf(b2f(Sb[(size_t)mi * Ndim]) - st.x) * st.y;
      acc += p;
      pk[jj] = f2b(p);
    }
    *reinterpret_cast<us8*>(&P_s[l * K3_PAD + w * 64 + i8 * 8]) = pk;
  }
  cs[w][l] = acc;
  __syncthreads();
  if (w == 0) rtot[l] = 1.0f / (1e-9f + cs[0][l] + cs[1][l] + cs[2][l] + cs[3][l]);
  __syncthreads();
  const int mo = (t & 31) * 8;
#pragma unroll
  for (int j = 0; j < 8; ++j) {
    const int n = (t >> 5) + j * 8;
    const float rc = rtot[n];
    us8 pv = *reinterpret_cast<const us8*>(&P_s[n * K3_PAD + mo]);
    us8 o;
#pragma unroll
    for (int q = 0; q < 8; ++q) o[q] = f2b(b2f(pv[q]) * rc);
    *reinterpret_cast<us8*>(gPT + ((size_t)b * Ndim + n0 + n) * Mdim + mo) = o;
  }
}

// ---------------- K4: out = x + Wv * Pn  (R2 structure restored) -----------
// 64x64 tile, grid (N/64, C/64, B) = 8192 blocks, ~4 blocks/CU via 34.8KB
// LDS. Both operands staged per 128-K-chunk from bf16 (us8 vector loads),
// pad 136 (verified: frag reads hit 8 distinct bank-quads = conflict-free
// minimum for b128). Block-level TLP hides all staging latency.
#define K4_P 136

__global__ __launch_bounds__(256) void k4_gemm2(
    const float* __restrict__ gx, const unsigned short* __restrict__ gWvB,
    const unsigned short* __restrict__ gPT, float* __restrict__ gout) {
  __shared__ unsigned short Wv_s[64 * K4_P];
  __shared__ unsigned short PT_s[64 * K4_P];
  const int t = threadIdx.x;
  const int b = blockIdx.z;
  const int c0 = blockIdx.y * 64;
  const int n0 = blockIdx.x * 64;
  const int w = t >> 6;
  const int lane = t & 63;
  const int lr = lane & 15;
  const int lg = lane >> 4;
  const int wc = (w >> 1) * 32;
  const int wn = (w & 1) * 32;

  f32x4 acc[2][2] = {};

  for (int ck = 0; ck < Mdim; ck += 128) {
    // stage Wv[c0..+63][ck..+127] (bf16, us8 vector loads)
#pragma unroll
    for (int i = 0; i < 4; ++i) {
      int q = i * 256 + t;
      int r = q >> 4;
      int mq = (q & 15) * 8;
      us8 u = *reinterpret_cast<const us8*>(gWvB + (size_t)(c0 + r) * Mdim + ck + mq);
      *reinterpret_cast<us8*>(&Wv_s[r * K4_P + mq]) = u;
    }
    // stage PT[b][n0..+63][ck..+127] (bf16)
#pragma unroll
    for (int i = 0; i < 4; ++i) {
      int q = i * 256 + t;
      int r = q >> 4;
      int mq = (q & 15) * 8;
      us8 u = *reinterpret_cast<const us8*>(gPT + ((size_t)b * Ndim + n0 + r) * Mdim + ck + mq);
      *reinterpret_cast<us8*>(&PT_s[r * K4_P + mq]) = u;
    }
    __syncthreads();
#pragma unroll
    for (int kk = 0; kk < 128; kk += 32) {
      bf16x8 af[2], bfr[2];
#pragma unroll
      for (int ci = 0; ci < 2; ++ci)
        af[ci] = *reinterpret_cast<const bf16x8*>(
            &Wv_s[(wc + ci * 16 + lr) * K4_P + kk + lg * 8]);
#pragma unroll
      for (int ni = 0; ni < 2; ++ni)
        bfr[ni] = *reinterpret_cast<const bf16x8*>(
            &PT_s[(wn + ni * 16 + lr) * K4_P + kk + lg * 8]);
#pragma unroll
      for (int ci = 0; ci < 2; ++ci)
#pragma unroll
        for (int ni = 0; ni < 2; ++ni)
          acc[ci][ni] = __builtin_amdgcn_mfma_f32_16x16x32_bf16(
              af[ci], bfr[ni], acc[ci][ni], 0, 0, 0);
    }
    __syncthreads();
  }
#pragma unroll
  for (int ci = 0; ci < 2; ++ci)
#pragma unroll
    for (int ni = 0; ni < 2; ++ni)
#pragma unroll
      for (int r = 0; r < 4; ++r) {
        int c = c0 + wc + ci * 16 + lg * 4 + r;
        int n = n0 + wn + ni * 16 + lr;
        size_t idx = ((size_t)b * Cdim + c) * Ndim + n;
        gout[idx] = gx[idx] + acc[ci][ni][r];
      }
}

extern "C" void kernel_launch(void* const* d_in, const int* in_sizes, int n_in,
                              void* d_out, int out_size, void* d_ws, size_t ws_size,
                              hipStream_t stream) {
  const float* x = (const float*)d_in[0];
  const float* Wk = (const float*)d_in[1];
  const float* Wv = (const float*)d_in[2];
  float* out = (float*)d_out;

  unsigned short* S = (unsigned short*)d_ws;                    // [B][M][N] bf16
  unsigned short* PT = S + (size_t)Bdim * Mdim * Ndim;          // [B][N][M] bf16
  float2* stats = (float2*)(PT + (size_t)Bdim * Ndim * Mdim);   // [B][M]
  unsigned short* WkB = (unsigned short*)(stats + Bdim * Mdim); // [M][C] bf16
  unsigned short* WvB = WkB + Mdim * Cdim;                      // [C][M] bf16

  k0_convert<<<dim3((Mdim * Cdim) / 1024), 256, 0, stream>>>(Wk, Wv, WkB, WvB);
  k1_gemm1<<<dim3(Ndim / 128, Mdim / 128, Bdim), 256, 0, stream>>>(x, WkB, S);
  k2_rowstats<<<dim3(Mdim, Bdim), 256, 0, stream>>>(S, stats);
  k3_norm<<<dim3(Ndim / 64, Bdim), 256, 0, stream>>>(S, stats, PT);
  k4_gemm2<<<dim3(Ndim / 64, Cdim / 64, Bdim), 256, 0, stream>>>(x, WvB, PT, out);
}